// Round 4
// baseline (132.775 us; speedup 1.0000x reference)
//
#include <hip/hip_runtime.h>

typedef unsigned short u16;
typedef unsigned int u32;
typedef float f32x4 __attribute__((ext_vector_type(4)));
typedef short s16x8 __attribute__((ext_vector_type(8)));

#define MFMA_BF16(a, b, c) __builtin_amdgcn_mfma_f32_16x16x32_bf16((a), (b), (c), 0, 0, 0)

// Problem constants: B=8, T=2048, D=1024, HS=64; scale = 1/sqrt(2048) (per reference!)

__device__ __forceinline__ u16 f2bf(float f) {
  union { float f; u32 u; } v; v.f = f;
  u32 u = v.u;
  return (u16)((u + 0x7FFFu + ((u >> 16) & 1u)) >> 16);  // RNE f32->bf16
}
__device__ __forceinline__ u16 f2bf_t(float f) {  // truncating f32->bf16 (P tile only)
  union { float f; u32 u; } v; v.f = f;
  return (u16)(v.u >> 16);
}

// ---- Kernel 1: W [1024][64] f32 x3 -> Wt bf16 [192][1024], LDS transpose, coalesced both sides.
// 48 blocks: m = bid>>4 (matrix), d0 = (bid&15)*64 (d-chunk).
__global__ __launch_bounds__(256) void wt_convert(const float* __restrict__ Wq,
                                                  const float* __restrict__ Wk,
                                                  const float* __restrict__ Wv,
                                                  u16* __restrict__ Wt) {
  __shared__ u16 Ls[64][70];  // 140B rows (35 dwords, odd -> d-groups split banks)
  const int bid = blockIdx.x;
  const int m = bid >> 4, d0 = (bid & 15) * 64;
  const float* W = (m == 0) ? Wq : (m == 1) ? Wk : Wv;
  const int t = threadIdx.x;
  {
    const int dr = t >> 2, hc = (t & 3) * 16;
    const float4* src = (const float4*)(W + (size_t)(d0 + dr) * 64 + hc);
    float4 f0 = src[0], f1 = src[1], f2 = src[2], f3 = src[3];
    float fl[16] = {f0.x, f0.y, f0.z, f0.w, f1.x, f1.y, f1.z, f1.w,
                    f2.x, f2.y, f2.z, f2.w, f3.x, f3.y, f3.z, f3.w};
#pragma unroll
    for (int j = 0; j < 8; ++j) {
      u32 pk = (u32)f2bf(fl[2 * j]) | ((u32)f2bf(fl[2 * j + 1]) << 16);
      *(u32*)&Ls[dr][hc + 2 * j] = pk;
    }
  }
  __syncthreads();
  {
    const int h = t >> 2, dcs = (t & 3) * 16;
    u32 po[8];
#pragma unroll
    for (int j = 0; j < 8; ++j)
      po[j] = (u32)Ls[dcs + 2 * j][h] | ((u32)Ls[dcs + 2 * j + 1][h] << 16);
    uint4* dst = (uint4*)&Wt[(size_t)(m * 64 + h) * 1024 + d0 + dcs];
    dst[0] = make_uint4(po[0], po[1], po[2], po[3]);
    dst[1] = make_uint4(po[4], po[5], po[6], po[7]);
  }
}

// ---- Kernel 2: QKV projection. C[16384,192] = X[16384,1024] @ W[1024,192], bf16 MFMA.
// 512 threads (8 waves), BM=32, grid=512. X staged in LDS (double-buffered, 9KB);
// W B-fragments read DIRECTLY from global (L1/L2-hit; k-slice 24KB fits L1) with
// 1-step register prefetch. One barrier per k-step.
// Outputs: q,k bf16 [B*T][64] row-major; v stored TRANSPOSED as vT bf16 [B*64][2048].
__global__ __launch_bounds__(512, 4) void qkv_gemm(const float* __restrict__ x,
                                                   const u16* __restrict__ Wt,
                                                   u16* __restrict__ qo,
                                                   u16* __restrict__ ko,
                                                   u16* __restrict__ vTo) {
  __shared__ u16 Xs[2][32][72];  // 144B rows: 16B-aligned b128, uniform banks
  const int tid = threadIdx.x;
  const int lane = tid & 63, w = tid >> 6;
  const int lc = lane & 15, hi = lane >> 4;
  const int m0 = blockIdx.x * 32;
  const int msub = w >> 2;        // 0..1
  const int nbase = (w & 3) * 3;  // n-tiles [nbase, nbase+3)

  f32x4 acc[3];
#pragma unroll
  for (int i = 0; i < 3; ++i) acc[i] = (f32x4){0.f, 0.f, 0.f, 0.f};

  const int xrow = tid >> 4, xcol = (tid & 15) * 4;  // X stage: 4 f32/thread
  // B-frag base offsets (elements), +k0 per step
  size_t bofs[6];
#pragma unroll
  for (int j = 0; j < 3; ++j)
#pragma unroll
    for (int ks = 0; ks < 2; ++ks)
      bofs[j * 2 + ks] = (size_t)((nbase + j) * 16 + lc) * 1024 + ks * 32 + hi * 8;

  float4 xr;
  s16x8 bc[6], bn[6];
  // prologue: t=0 loads
  xr = *(const float4*)(x + (size_t)(m0 + xrow) * 1024 + xcol);
#pragma unroll
  for (int i = 0; i < 6; ++i) bc[i] = *(const s16x8*)(Wt + bofs[i]);
  {
    u32 plo = (u32)f2bf(xr.x) | ((u32)f2bf(xr.y) << 16);
    u32 phi = (u32)f2bf(xr.z) | ((u32)f2bf(xr.w) << 16);
    *(uint2*)&Xs[0][xrow][xcol] = make_uint2(plo, phi);
  }
  __syncthreads();
  int cur = 0;

  for (int t = 0; t < 16; ++t) {
    if (t < 15) {
      const int k1 = (t + 1) * 64;
      xr = *(const float4*)(x + (size_t)(m0 + xrow) * 1024 + k1 + xcol);
#pragma unroll
      for (int i = 0; i < 6; ++i) bn[i] = *(const s16x8*)(Wt + bofs[i] + k1);
    }
#pragma unroll
    for (int ksub = 0; ksub < 2; ++ksub) {
      s16x8 a = *(const s16x8*)&Xs[cur][msub * 16 + lc][ksub * 32 + hi * 8];
#pragma unroll
      for (int j = 0; j < 3; ++j) acc[j] = MFMA_BF16(a, bc[j * 2 + ksub], acc[j]);
    }
    if (t < 15) {
      u32 plo = (u32)f2bf(xr.x) | ((u32)f2bf(xr.y) << 16);
      u32 phi = (u32)f2bf(xr.z) | ((u32)f2bf(xr.w) << 16);
      *(uint2*)&Xs[cur ^ 1][xrow][xcol] = make_uint2(plo, phi);
#pragma unroll
      for (int i = 0; i < 6; ++i) bc[i] = bn[i];
      __syncthreads();
      cur ^= 1;
    }
  }

  // epilogue: C layout col=lane&15, row=(lane>>4)*4+r
#pragma unroll
  for (int j = 0; j < 3; ++j) {
    int nt = nbase + j;
#pragma unroll
    for (int r = 0; r < 4; ++r) {
      int gr = m0 + msub * 16 + hi * 4 + r;
      u16 val = f2bf(acc[j][r]);
      int n = nt * 16 + lc;
      if (nt < 4) {
        qo[gr * 64 + n] = val;
      } else if (nt < 8) {
        ko[gr * 64 + (n - 64)] = val;
      } else {
        int b = gr >> 11, t2 = gr & 2047;
        vTo[((b << 6) + (n - 128)) * 2048 + t2] = val;
      }
    }
  }
}

// ---- Kernel 3: causal flash attention, no-max softmax (scores bounded: ~N(0,0.18^2)).
// grid 512 x 1024 threads (16 waves). Block = batch b (XCD-pinned) + subtile pair
// (u, 127-u): 2 q-subtiles of 16 rows x 8-way KV split each -> uniform load.
// LDS: per-wave UNION of P (in-loop) and Po (merge) -> 68.6KB -> 2 blocks/CU
// = 32 waves/CU = 8 waves/SIMD. VGPR pinned <=64 via launch_bounds.
__global__ __launch_bounds__(1024, 8) void attn_fwd(const u16* __restrict__ qb,
                                                    const u16* __restrict__ kb,
                                                    const u16* __restrict__ vT,
                                                    float* __restrict__ out) {
  __shared__ u32 U[16][1056];   // per-wave 4224B: P [16][40] u16 | Po [16][66] f32
  __shared__ float Pl[16][16];  // per-wave denominator partials
  const int tid = threadIdx.x, lane = tid & 63, w = tid >> 6;
  const int lc = lane & 15, hi = lane >> 4;
  const int q = w >> 3, s = w & 7;  // q-subtile select, kv-split index (8-way)
  const int bid = blockIdx.x;
  const int b = bid & 7, u = bid >> 3;           // batch (=XCD), pair id 0..63
  const int qbase = (q ? (127 - u) : u) * 16;    // subtile pair (u, 127-u)
  const int brow = b * 2048;
  u16* Pw = (u16*)&U[w][0];

  // Q A-fragments (A[16,32]: lane -> row=lane&15, k=(lane>>4)*8), hoisted
  const u16* qrow = qb + (size_t)(brow + qbase + lc) * 64;
  s16x8 aq0 = *(const s16x8*)(qrow + hi * 8);
  s16x8 aq1 = *(const s16x8*)(qrow + 32 + hi * 8);

  f32x4 o[4];
  float lrow[4] = {0.f, 0.f, 0.f, 0.f};
#pragma unroll
  for (int i = 0; i < 4; ++i) o[i] = (f32x4){0.f, 0.f, 0.f, 0.f};

  const float SL = 0.031879357f;    // (1/sqrt(2048)) * log2(e)
  const int n = (qbase + 47) >> 5;  // ceil((qbase+16)/32) kv-tiles of 32
  const int c = (n + 7) >> 3;       // chunk per split-wave (8-way)
  const int it0 = s * c;
  const int it1 = min(it0 + c, n);

  const u16* kbase = kb + (size_t)brow * 64;
  s16x8 k00, k01, k10, k11;
  if (it0 < it1) {
    const u16* krow = kbase + (size_t)(it0 * 32) * 64;
    k00 = *(const s16x8*)(krow + lc * 64 + hi * 8);
    k01 = *(const s16x8*)(krow + lc * 64 + 32 + hi * 8);
    k10 = *(const s16x8*)(krow + (16 + lc) * 64 + hi * 8);
    k11 = *(const s16x8*)(krow + (16 + lc) * 64 + 32 + hi * 8);
  }

  for (int it = it0; it < it1; ++it) {
    const int kvb = it * 32;
    // prefetch next K tile (wave-uniform branch)
    s16x8 n00, n01, n10, n11;
    if (it + 1 < it1) {
      const u16* krow = kbase + (size_t)(kvb + 32) * 64;
      n00 = *(const s16x8*)(krow + lc * 64 + hi * 8);
      n01 = *(const s16x8*)(krow + lc * 64 + 32 + hi * 8);
      n10 = *(const s16x8*)(krow + (16 + lc) * 64 + hi * 8);
      n11 = *(const s16x8*)(krow + (16 + lc) * 64 + 32 + hi * 8);
    }
    f32x4 s0 = {0.f, 0.f, 0.f, 0.f}, s1 = {0.f, 0.f, 0.f, 0.f};
    s0 = MFMA_BF16(aq0, k00, s0);
    s0 = MFMA_BF16(aq1, k01, s0);
    s1 = MFMA_BF16(aq0, k10, s1);
    s1 = MFMA_BF16(aq1, k11, s1);

    // V loads hoisted (independent of softmax)
    s16x8 bv[4];
#pragma unroll
    for (int nt = 0; nt < 4; ++nt)
      bv[nt] = *(const s16x8*)&vT[(size_t)(b * 64 + nt * 16 + lc) * 2048 + kvb + hi * 8];

    if (kvb + 31 <= qbase) {  // tile fully below diagonal: no masks
#pragma unroll
      for (int r = 0; r < 4; ++r) {
        float p0 = exp2f(s0[r] * SL);
        float p1 = exp2f(s1[r] * SL);
        lrow[r] += p0 + p1;
        Pw[(hi * 4 + r) * 40 + lc] = f2bf_t(p0);
        Pw[(hi * 4 + r) * 40 + 16 + lc] = f2bf_t(p1);
      }
    } else {
#pragma unroll
      for (int r = 0; r < 4; ++r) {
        const int qt = qbase + hi * 4 + r;
        const int kv0 = kvb + lc;
        float p0 = (kv0 <= qt) ? exp2f(s0[r] * SL) : 0.f;
        float p1 = (kv0 + 16 <= qt) ? exp2f(s1[r] * SL) : 0.f;
        lrow[r] += p0 + p1;
        Pw[(hi * 4 + r) * 40 + lc] = f2bf_t(p0);
        Pw[(hi * 4 + r) * 40 + 16 + lc] = f2bf_t(p1);
      }
    }
    // wave-local LDS write->read fence (per-wave buffer; DS in-order per wave)
    asm volatile("s_waitcnt lgkmcnt(0)" ::: "memory");
    s16x8 pa = *(const s16x8*)&Pw[lc * 40 + hi * 8];  // A-fragment of P[16,32]
#pragma unroll
    for (int nt = 0; nt < 4; ++nt) o[nt] = MFMA_BF16(pa, bv[nt], o[nt]);

    if (it + 1 < it1) { k00 = n00; k01 = n01; k10 = n10; k11 = n11; }
  }

  // cross-lane denominator reduce, once
#pragma unroll
  for (int r = 0; r < 4; ++r) {
    lrow[r] += __shfl_xor(lrow[r], 1);
    lrow[r] += __shfl_xor(lrow[r], 2);
    lrow[r] += __shfl_xor(lrow[r], 4);
    lrow[r] += __shfl_xor(lrow[r], 8);
  }

  // publish partials (Po overlays P — P is dead for this wave now)
  if (lc == 0) {
#pragma unroll
    for (int r = 0; r < 4; ++r) Pl[w][hi * 4 + r] = lrow[r];
  }
  float* Pow = (float*)&U[w][0];
#pragma unroll
  for (int nt = 0; nt < 4; ++nt) {
#pragma unroll
    for (int r = 0; r < 4; ++r) Pow[(hi * 4 + r) * 66 + nt * 16 + lc] = o[nt][r];
  }
  __syncthreads();

  // merge: plain sums over the 8 split partials; waves s<4 handle 4 rows each
  if (s < 4) {
#pragma unroll
    for (int rr = 0; rr < 4; ++rr) {
      const int row = s * 4 + rr;
      float L = 0.f, val = 0.f;
#pragma unroll
      for (int j = 0; j < 8; ++j) {
        L += Pl[q * 8 + j][row];
        val += ((const float*)&U[q * 8 + j][0])[row * 66 + lane];
      }
      out[(size_t)(brow + qbase + row) * 64 + lane] = val / L;
    }
  }
}

extern "C" void kernel_launch(void* const* d_in, const int* in_sizes, int n_in,
                              void* d_out, int out_size, void* d_ws, size_t ws_size,
                              hipStream_t stream) {
  (void)in_sizes; (void)n_in; (void)out_size; (void)ws_size;
  const float* x = (const float*)d_in[0];
  const float* Wq = (const float*)d_in[1];
  const float* Wk = (const float*)d_in[2];
  const float* Wv = (const float*)d_in[3];
  float* out = (float*)d_out;

  u16* wsu = (u16*)d_ws;
  u16* Wt = wsu;                      // 192*1024
  u16* qb = Wt + 192 * 1024;          // 8*2048*64
  u16* kb = qb + 8 * 2048 * 64;       // 8*2048*64
  u16* vT = kb + 8 * 2048 * 64;       // 8*64*2048
  // total ws use: 6,684,672 bytes

  wt_convert<<<48, 256, 0, stream>>>(Wq, Wk, Wv, Wt);
  qkv_gemm<<<512, 512, 0, stream>>>(x, Wt, qb, kb, vT);
  attn_fwd<<<512, 1024, 0, stream>>>(qb, kb, vT, out);
}

// Round 5
// 83.546 us; speedup vs baseline: 1.5892x; 1.5892x over previous
//
#include <hip/hip_runtime.h>

typedef unsigned short u16;
typedef unsigned int u32;
typedef float f32x4 __attribute__((ext_vector_type(4)));
typedef short s16x8 __attribute__((ext_vector_type(8)));

#define MFMA_BF16(a, b, c) __builtin_amdgcn_mfma_f32_16x16x32_bf16((a), (b), (c), 0, 0, 0)

// Problem constants: B=8, T=2048, D=1024, HS=64; scale = 1/sqrt(2048) (per reference!)

__device__ __forceinline__ u16 f2bf(float f) {
  union { float f; u32 u; } v; v.f = f;
  u32 u = v.u;
  return (u16)((u + 0x7FFFu + ((u >> 16) & 1u)) >> 16);  // RNE f32->bf16
}
__device__ __forceinline__ u16 f2bf_t(float f) {  // truncating f32->bf16 (P tile only)
  union { float f; u32 u; } v; v.f = f;
  return (u16)(v.u >> 16);
}

// ---- Kernel 1: W [1024][64] f32 x3 -> Wt bf16 [192][1024], LDS transpose, coalesced both sides.
__global__ __launch_bounds__(256) void wt_convert(const float* __restrict__ Wq,
                                                  const float* __restrict__ Wk,
                                                  const float* __restrict__ Wv,
                                                  u16* __restrict__ Wt) {
  __shared__ u16 Ls[64][70];
  const int bid = blockIdx.x;
  const int m = bid >> 4, d0 = (bid & 15) * 64;
  const float* W = (m == 0) ? Wq : (m == 1) ? Wk : Wv;
  const int t = threadIdx.x;
  {
    const int dr = t >> 2, hc = (t & 3) * 16;
    const float4* src = (const float4*)(W + (size_t)(d0 + dr) * 64 + hc);
    float4 f0 = src[0], f1 = src[1], f2 = src[2], f3 = src[3];
    float fl[16] = {f0.x, f0.y, f0.z, f0.w, f1.x, f1.y, f1.z, f1.w,
                    f2.x, f2.y, f2.z, f2.w, f3.x, f3.y, f3.z, f3.w};
#pragma unroll
    for (int j = 0; j < 8; ++j) {
      u32 pk = (u32)f2bf(fl[2 * j]) | ((u32)f2bf(fl[2 * j + 1]) << 16);
      *(u32*)&Ls[dr][hc + 2 * j] = pk;
    }
  }
  __syncthreads();
  {
    const int h = t >> 2, dcs = (t & 3) * 16;
    u32 po[8];
#pragma unroll
    for (int j = 0; j < 8; ++j)
      po[j] = (u32)Ls[dcs + 2 * j][h] | ((u32)Ls[dcs + 2 * j + 1][h] << 16);
    uint4* dst = (uint4*)&Wt[(size_t)(m * 64 + h) * 1024 + d0 + dcs];
    dst[0] = make_uint4(po[0], po[1], po[2], po[3]);
    dst[1] = make_uint4(po[4], po[5], po[6], po[7]);
  }
}

// ---- Kernel 2: QKV projection (unchanged from round 3: passed, ~15us).
__global__ __launch_bounds__(512, 4) void qkv_gemm(const float* __restrict__ x,
                                                   const u16* __restrict__ Wt,
                                                   u16* __restrict__ qo,
                                                   u16* __restrict__ ko,
                                                   u16* __restrict__ vTo) {
  __shared__ u16 Xs[2][32][72];
  const int tid = threadIdx.x;
  const int lane = tid & 63, w = tid >> 6;
  const int lc = lane & 15, hi = lane >> 4;
  const int m0 = blockIdx.x * 32;
  const int msub = w >> 2;
  const int nbase = (w & 3) * 3;

  f32x4 acc[3];
#pragma unroll
  for (int i = 0; i < 3; ++i) acc[i] = (f32x4){0.f, 0.f, 0.f, 0.f};

  const int xrow = tid >> 4, xcol = (tid & 15) * 4;
  size_t bofs[6];
#pragma unroll
  for (int j = 0; j < 3; ++j)
#pragma unroll
    for (int ks = 0; ks < 2; ++ks)
      bofs[j * 2 + ks] = (size_t)((nbase + j) * 16 + lc) * 1024 + ks * 32 + hi * 8;

  float4 xr;
  s16x8 bc[6], bn[6];
  xr = *(const float4*)(x + (size_t)(m0 + xrow) * 1024 + xcol);
#pragma unroll
  for (int i = 0; i < 6; ++i) bc[i] = *(const s16x8*)(Wt + bofs[i]);
  {
    u32 plo = (u32)f2bf(xr.x) | ((u32)f2bf(xr.y) << 16);
    u32 phi = (u32)f2bf(xr.z) | ((u32)f2bf(xr.w) << 16);
    *(uint2*)&Xs[0][xrow][xcol] = make_uint2(plo, phi);
  }
  __syncthreads();
  int cur = 0;

  for (int t = 0; t < 16; ++t) {
    if (t < 15) {
      const int k1 = (t + 1) * 64;
      xr = *(const float4*)(x + (size_t)(m0 + xrow) * 1024 + k1 + xcol);
#pragma unroll
      for (int i = 0; i < 6; ++i) bn[i] = *(const s16x8*)(Wt + bofs[i] + k1);
    }
#pragma unroll
    for (int ksub = 0; ksub < 2; ++ksub) {
      s16x8 a = *(const s16x8*)&Xs[cur][msub * 16 + lc][ksub * 32 + hi * 8];
#pragma unroll
      for (int j = 0; j < 3; ++j) acc[j] = MFMA_BF16(a, bc[j * 2 + ksub], acc[j]);
    }
    if (t < 15) {
      u32 plo = (u32)f2bf(xr.x) | ((u32)f2bf(xr.y) << 16);
      u32 phi = (u32)f2bf(xr.z) | ((u32)f2bf(xr.w) << 16);
      *(uint2*)&Xs[cur ^ 1][xrow][xcol] = make_uint2(plo, phi);
#pragma unroll
      for (int i = 0; i < 6; ++i) bc[i] = bn[i];
      __syncthreads();
      cur ^= 1;
    }
  }

#pragma unroll
  for (int j = 0; j < 3; ++j) {
    int nt = nbase + j;
#pragma unroll
    for (int r = 0; r < 4; ++r) {
      int gr = m0 + msub * 16 + hi * 4 + r;
      u16 val = f2bf(acc[j][r]);
      int n = nt * 16 + lc;
      if (nt < 4) {
        qo[gr * 64 + n] = val;
      } else if (nt < 8) {
        ko[gr * 64 + (n - 64)] = val;
      } else {
        int b = gr >> 11, t2 = gr & 2047;
        vTo[((b << 6) + (n - 128)) * 2048 + t2] = val;
      }
    }
  }
}

// ---- Kernel 3: causal flash attention, no-max softmax. 256 threads = 4 waves.
// Block = one 32-row q-tile (2 subtiles of 16) of batch b; 4 waves = 4-way KV split;
// LDS merge. Heavy-first launch order: v = 63 - (bid>>3); b = bid&7 (XCD affinity).
// Per wave-iter: 32q x 32kv = 16 MFMA; K/V frags amortized over 2 q-subtiles.
// LDS 34.3KB -> 4 blocks/CU; VGPR target ~120 (<=128 class) -> 16 waves/CU, NO spill.
__global__ __launch_bounds__(256, 2) void attn_fwd(const u16* __restrict__ qb,
                                                   const u16* __restrict__ kb,
                                                   const u16* __restrict__ vT,
                                                   float* __restrict__ out) {
  __shared__ float PoS[4][32][66];  // per-wave merge buffer; P tile [32][40]u16 unioned in
  __shared__ float Pl[4][32];       // per-wave denominator partials
  const int tid = threadIdx.x, lane = tid & 63, w = tid >> 6;
  const int lc = lane & 15, hi = lane >> 4;
  const int bid = blockIdx.x;
  const int b = bid & 7, v = 63 - (bid >> 3);  // batch, q-tile id (heavy-first)
  const int q0 = v * 32;                       // q-tile base row within batch
  const int brow = b * 2048;
  u16* Pw = (u16*)&PoS[w][0][0];  // [32][40] u16 view, per-wave

  // Q A-fragments: 2 subtiles x 2 k-halves (A[16,64]: lane row=lc, k=hi*8 within half)
  s16x8 aq[2][2];
#pragma unroll
  for (int sub = 0; sub < 2; ++sub) {
    const u16* qrow = qb + (size_t)(brow + q0 + sub * 16 + lc) * 64;
    aq[sub][0] = *(const s16x8*)(qrow + hi * 8);
    aq[sub][1] = *(const s16x8*)(qrow + 32 + hi * 8);
  }

  f32x4 o[2][4];
  float lrow[2][4];
#pragma unroll
  for (int sub = 0; sub < 2; ++sub)
#pragma unroll
    for (int i = 0; i < 4; ++i) {
      o[sub][i] = (f32x4){0.f, 0.f, 0.f, 0.f};
      lrow[sub][i] = 0.f;
    }

  const float SL = 0.031879357f;  // (1/sqrt(2048)) * log2(e)
  const int nk = v + 1;           // causal kv-tiles of 32 for this q-tile
  const int c = (nk + 3) >> 2;    // chunk per split-wave (4-way)
  const int s = w;
  const int it0 = s * c;
  const int it1 = min(it0 + c, nk);

  const u16* kbase = kb + (size_t)brow * 64;

  for (int it = it0; it < it1; ++it) {
    const int kvb = it * 32;
    // K fragments: 2 kv-subtiles x 2 k-halves
    const u16* krow0 = kbase + (size_t)(kvb + lc) * 64;
    const u16* krow1 = kbase + (size_t)(kvb + 16 + lc) * 64;
    s16x8 k00 = *(const s16x8*)(krow0 + hi * 8);
    s16x8 k01 = *(const s16x8*)(krow0 + 32 + hi * 8);
    s16x8 k10 = *(const s16x8*)(krow1 + hi * 8);
    s16x8 k11 = *(const s16x8*)(krow1 + 32 + hi * 8);
    // V fragments (B[32,16] from vT: contiguous per lane) - issued early, used late
    s16x8 bv[4];
#pragma unroll
    for (int nt = 0; nt < 4; ++nt)
      bv[nt] = *(const s16x8*)&vT[(size_t)(b * 64 + nt * 16 + lc) * 2048 + kvb + hi * 8];

    f32x4 sc[2][2];
#pragma unroll
    for (int sub = 0; sub < 2; ++sub) {
      sc[sub][0] = (f32x4){0.f, 0.f, 0.f, 0.f};
      sc[sub][1] = (f32x4){0.f, 0.f, 0.f, 0.f};
      sc[sub][0] = MFMA_BF16(aq[sub][0], k00, sc[sub][0]);
      sc[sub][0] = MFMA_BF16(aq[sub][1], k01, sc[sub][0]);
      sc[sub][1] = MFMA_BF16(aq[sub][0], k10, sc[sub][1]);
      sc[sub][1] = MFMA_BF16(aq[sub][1], k11, sc[sub][1]);
    }

    if (kvb + 31 <= q0) {  // tile fully below diagonal: no masks
#pragma unroll
      for (int sub = 0; sub < 2; ++sub)
#pragma unroll
        for (int r = 0; r < 4; ++r) {
          float p0 = exp2f(sc[sub][0][r] * SL);
          float p1 = exp2f(sc[sub][1][r] * SL);
          lrow[sub][r] += p0 + p1;
          Pw[(sub * 16 + hi * 4 + r) * 40 + lc] = f2bf_t(p0);
          Pw[(sub * 16 + hi * 4 + r) * 40 + 16 + lc] = f2bf_t(p1);
        }
    } else {  // diagonal tile: causal masks
#pragma unroll
      for (int sub = 0; sub < 2; ++sub)
#pragma unroll
        for (int r = 0; r < 4; ++r) {
          const int qt = q0 + sub * 16 + hi * 4 + r;
          const int kv0 = kvb + lc;
          float p0 = (kv0 <= qt) ? exp2f(sc[sub][0][r] * SL) : 0.f;
          float p1 = (kv0 + 16 <= qt) ? exp2f(sc[sub][1][r] * SL) : 0.f;
          lrow[sub][r] += p0 + p1;
          Pw[(sub * 16 + hi * 4 + r) * 40 + lc] = f2bf_t(p0);
          Pw[(sub * 16 + hi * 4 + r) * 40 + 16 + lc] = f2bf_t(p1);
        }
    }
    // wave-local LDS write->read fence (per-wave buffer; DS in-order per wave)
    asm volatile("s_waitcnt lgkmcnt(0)" ::: "memory");
    s16x8 pa0 = *(const s16x8*)&Pw[lc * 40 + hi * 8];
    s16x8 pa1 = *(const s16x8*)&Pw[(16 + lc) * 40 + hi * 8];
#pragma unroll
    for (int nt = 0; nt < 4; ++nt) {
      o[0][nt] = MFMA_BF16(pa0, bv[nt], o[0][nt]);
      o[1][nt] = MFMA_BF16(pa1, bv[nt], o[1][nt]);
    }
  }

  // cross-lane denominator reduce, once
#pragma unroll
  for (int sub = 0; sub < 2; ++sub)
#pragma unroll
    for (int r = 0; r < 4; ++r) {
      float l = lrow[sub][r];
      l += __shfl_xor(l, 1);
      l += __shfl_xor(l, 2);
      l += __shfl_xor(l, 4);
      l += __shfl_xor(l, 8);
      lrow[sub][r] = l;
    }

  // publish partials (Po overlays P -- P is dead for this wave now)
  if (lc == 0) {
#pragma unroll
    for (int sub = 0; sub < 2; ++sub)
#pragma unroll
      for (int r = 0; r < 4; ++r) Pl[w][sub * 16 + hi * 4 + r] = lrow[sub][r];
  }
  float* Pow = &PoS[w][0][0];
#pragma unroll
  for (int sub = 0; sub < 2; ++sub)
#pragma unroll
    for (int nt = 0; nt < 4; ++nt)
#pragma unroll
      for (int r = 0; r < 4; ++r)
        Pow[(sub * 16 + hi * 4 + r) * 66 + nt * 16 + lc] = o[sub][nt][r];
  __syncthreads();

  // merge: plain sums over 4 split partials; wave w handles rows w*8 .. w*8+7
#pragma unroll
  for (int rr = 0; rr < 8; ++rr) {
    const int row = w * 8 + rr;
    float L = Pl[0][row] + Pl[1][row] + Pl[2][row] + Pl[3][row];
    float val = PoS[0][row][lane] + PoS[1][row][lane] + PoS[2][row][lane] + PoS[3][row][lane];
    out[(size_t)(brow + q0 + row) * 64 + lane] = val / L;
  }
}

extern "C" void kernel_launch(void* const* d_in, const int* in_sizes, int n_in,
                              void* d_out, int out_size, void* d_ws, size_t ws_size,
                              hipStream_t stream) {
  (void)in_sizes; (void)n_in; (void)out_size; (void)ws_size;
  const float* x = (const float*)d_in[0];
  const float* Wq = (const float*)d_in[1];
  const float* Wk = (const float*)d_in[2];
  const float* Wv = (const float*)d_in[3];
  float* out = (float*)d_out;

  u16* wsu = (u16*)d_ws;
  u16* Wt = wsu;                      // 192*1024
  u16* qb = Wt + 192 * 1024;          // 8*2048*64
  u16* kb = qb + 8 * 2048 * 64;       // 8*2048*64
  u16* vT = kb + 8 * 2048 * 64;       // 8*64*2048
  // total ws use: 6,684,672 bytes

  wt_convert<<<48, 256, 0, stream>>>(Wq, Wk, Wv, Wt);
  qkv_gemm<<<512, 512, 0, stream>>>(x, Wt, qb, kb, vT);
  attn_fwd<<<512, 256, 0, stream>>>(qb, kb, vT, out);
}

// Round 6
// 83.078 us; speedup vs baseline: 1.5982x; 1.0056x over previous
//
#include <hip/hip_runtime.h>

typedef unsigned short u16;
typedef unsigned int u32;
typedef float f32x4 __attribute__((ext_vector_type(4)));
typedef short s16x8 __attribute__((ext_vector_type(8)));

#define MFMA_BF16(a, b, c) __builtin_amdgcn_mfma_f32_16x16x32_bf16((a), (b), (c), 0, 0, 0)

// Problem constants: B=8, T=2048, D=1024, HS=64; scale = 1/sqrt(2048) (per reference!)

__device__ __forceinline__ u16 f2bf(float f) {
  union { float f; u32 u; } v; v.f = f;
  u32 u = v.u;
  return (u16)((u + 0x7FFFu + ((u >> 16) & 1u)) >> 16);  // RNE f32->bf16
}
__device__ __forceinline__ u16 f2bf_t(float f) {  // truncating f32->bf16 (P tile only)
  union { float f; u32 u; } v; v.f = f;
  return (u16)(v.u >> 16);
}

// ---- Kernel 1: W [1024][64] f32 x3 -> Wt bf16 [192][1024], LDS transpose, coalesced both sides.
__global__ __launch_bounds__(256) void wt_convert(const float* __restrict__ Wq,
                                                  const float* __restrict__ Wk,
                                                  const float* __restrict__ Wv,
                                                  u16* __restrict__ Wt) {
  __shared__ u16 Ls[64][70];
  const int bid = blockIdx.x;
  const int m = bid >> 4, d0 = (bid & 15) * 64;
  const float* W = (m == 0) ? Wq : (m == 1) ? Wk : Wv;
  const int t = threadIdx.x;
  {
    const int dr = t >> 2, hc = (t & 3) * 16;
    const float4* src = (const float4*)(W + (size_t)(d0 + dr) * 64 + hc);
    float4 f0 = src[0], f1 = src[1], f2 = src[2], f3 = src[3];
    float fl[16] = {f0.x, f0.y, f0.z, f0.w, f1.x, f1.y, f1.z, f1.w,
                    f2.x, f2.y, f2.z, f2.w, f3.x, f3.y, f3.z, f3.w};
#pragma unroll
    for (int j = 0; j < 8; ++j) {
      u32 pk = (u32)f2bf(fl[2 * j]) | ((u32)f2bf(fl[2 * j + 1]) << 16);
      *(u32*)&Ls[dr][hc + 2 * j] = pk;
    }
  }
  __syncthreads();
  {
    const int h = t >> 2, dcs = (t & 3) * 16;
    u32 po[8];
#pragma unroll
    for (int j = 0; j < 8; ++j)
      po[j] = (u32)Ls[dcs + 2 * j][h] | ((u32)Ls[dcs + 2 * j + 1][h] << 16);
    uint4* dst = (uint4*)&Wt[(size_t)(m * 64 + h) * 1024 + d0 + dcs];
    dst[0] = make_uint4(po[0], po[1], po[2], po[3]);
    dst[1] = make_uint4(po[4], po[5], po[6], po[7]);
  }
}

// ---- Kernel 2: QKV projection. C[16384,192] = X[16384,1024] @ W[1024,192], bf16 MFMA.
// 256 threads (4 waves), BM=16, grid=1024 -> 4 blocks/CU = 16 waves/CU = 4 waves/SIMD.
// Each wave: all 16 rows x 3 n-tiles (zero W redundancy in-block, acc only 12 regs).
// X staged in LDS (double-buffered, 4.6KB), 2-deep x prefetch, 1-step W prefetch,
// ONE barrier per k-step. NO min-waves hint: let the allocator take ~100 VGPRs (the
// round-5 regression was VGPR_Count=32 -> spill/load-sinking from the (512,4) cap).
__global__ __launch_bounds__(256) void qkv_gemm(const float* __restrict__ x,
                                                const u16* __restrict__ Wt,
                                                u16* __restrict__ qo,
                                                u16* __restrict__ ko,
                                                u16* __restrict__ vTo) {
  __shared__ u16 Xs[2][16][72];  // 144B rows: 16B-aligned b128 reads, 2-way banks (free)
  const int tid = threadIdx.x;
  const int lane = tid & 63, w = tid >> 6;
  const int lc = lane & 15, hi = lane >> 4;
  const int m0 = blockIdx.x * 16;
  const int nbase = w * 3;  // wave w -> n-tiles [3w, 3w+3)

  f32x4 acc[3];
#pragma unroll
  for (int i = 0; i < 3; ++i) acc[i] = (f32x4){0.f, 0.f, 0.f, 0.f};

  const int xrow = tid >> 4, xcol = (tid & 15) * 4;  // X stage: one float4/thread
  // W element offsets for 3 n-tiles x 2 ksub (32-bit; max 192*1024)
  int bofs[6];
#pragma unroll
  for (int j = 0; j < 3; ++j)
#pragma unroll
    for (int ks = 0; ks < 2; ++ks)
      bofs[j * 2 + ks] = ((nbase + j) * 16 + lc) * 1024 + ks * 32 + hi * 8;

  const float* xptr = x + (size_t)(m0 + xrow) * 1024 + xcol;
  auto pack_write = [&](int bf, float4 v) {
    u32 plo = (u32)f2bf(v.x) | ((u32)f2bf(v.y) << 16);
    u32 phi = (u32)f2bf(v.z) | ((u32)f2bf(v.w) << 16);
    *(uint2*)&Xs[bf][xrow][xcol] = make_uint2(plo, phi);
  };

  // prologue: t=0 staged; xa = t=1 data; bc = t=0 W frags
  float4 x0 = *(const float4*)xptr;
  float4 xa = *(const float4*)(xptr + 64);
  s16x8 bc[6], bn[6];
#pragma unroll
  for (int i = 0; i < 6; ++i) bc[i] = *(const s16x8*)(Wt + bofs[i]);
  pack_write(0, x0);
  __syncthreads();
  int cur = 0;

  for (int t = 0; t < 16; ++t) {
    float4 xb;
    if (t < 14) xb = *(const float4*)(xptr + (t + 2) * 64);  // 2-deep x prefetch
    if (t < 15) {
      const int k1 = (t + 1) * 64;
#pragma unroll
      for (int i = 0; i < 6; ++i) bn[i] = *(const s16x8*)(Wt + bofs[i] + k1);
    }
#pragma unroll
    for (int ksub = 0; ksub < 2; ++ksub) {
      s16x8 a = *(const s16x8*)&Xs[cur][lc][ksub * 32 + hi * 8];
#pragma unroll
      for (int j = 0; j < 3; ++j) acc[j] = MFMA_BF16(a, bc[j * 2 + ksub], acc[j]);
    }
    if (t < 15) {
      pack_write(cur ^ 1, xa);  // stage t+1
#pragma unroll
      for (int i = 0; i < 6; ++i) bc[i] = bn[i];
      __syncthreads();
      xa = xb;
      cur ^= 1;
    }
  }

  // epilogue: C layout col=lane&15, row=(lane>>4)*4+r
#pragma unroll
  for (int j = 0; j < 3; ++j) {
    int nt = nbase + j;
#pragma unroll
    for (int r = 0; r < 4; ++r) {
      int gr = m0 + hi * 4 + r;
      u16 val = f2bf(acc[j][r]);
      int n = nt * 16 + lc;
      if (nt < 4) {
        qo[gr * 64 + n] = val;
      } else if (nt < 8) {
        ko[gr * 64 + (n - 64)] = val;
      } else {
        int b = gr >> 11, t2 = gr & 2047;
        vTo[((b << 6) + (n - 128)) * 2048 + t2] = val;
      }
    }
  }
}

// ---- Kernel 3: causal flash attention, no-max softmax. 256 threads = 4 waves.
// (unchanged from round 5: ~25us)
__global__ __launch_bounds__(256, 2) void attn_fwd(const u16* __restrict__ qb,
                                                   const u16* __restrict__ kb,
                                                   const u16* __restrict__ vT,
                                                   float* __restrict__ out) {
  __shared__ float PoS[4][32][66];  // per-wave merge buffer; P tile [32][40]u16 unioned in
  __shared__ float Pl[4][32];       // per-wave denominator partials
  const int tid = threadIdx.x, lane = tid & 63, w = tid >> 6;
  const int lc = lane & 15, hi = lane >> 4;
  const int bid = blockIdx.x;
  const int b = bid & 7, v = 63 - (bid >> 3);  // batch, q-tile id (heavy-first)
  const int q0 = v * 32;                       // q-tile base row within batch
  const int brow = b * 2048;
  u16* Pw = (u16*)&PoS[w][0][0];  // [32][40] u16 view, per-wave

  s16x8 aq[2][2];
#pragma unroll
  for (int sub = 0; sub < 2; ++sub) {
    const u16* qrow = qb + (size_t)(brow + q0 + sub * 16 + lc) * 64;
    aq[sub][0] = *(const s16x8*)(qrow + hi * 8);
    aq[sub][1] = *(const s16x8*)(qrow + 32 + hi * 8);
  }

  f32x4 o[2][4];
  float lrow[2][4];
#pragma unroll
  for (int sub = 0; sub < 2; ++sub)
#pragma unroll
    for (int i = 0; i < 4; ++i) {
      o[sub][i] = (f32x4){0.f, 0.f, 0.f, 0.f};
      lrow[sub][i] = 0.f;
    }

  const float SL = 0.031879357f;  // (1/sqrt(2048)) * log2(e)
  const int nk = v + 1;           // causal kv-tiles of 32 for this q-tile
  const int c = (nk + 3) >> 2;    // chunk per split-wave (4-way)
  const int s = w;
  const int it0 = s * c;
  const int it1 = min(it0 + c, nk);

  const u16* kbase = kb + (size_t)brow * 64;

  for (int it = it0; it < it1; ++it) {
    const int kvb = it * 32;
    const u16* krow0 = kbase + (size_t)(kvb + lc) * 64;
    const u16* krow1 = kbase + (size_t)(kvb + 16 + lc) * 64;
    s16x8 k00 = *(const s16x8*)(krow0 + hi * 8);
    s16x8 k01 = *(const s16x8*)(krow0 + 32 + hi * 8);
    s16x8 k10 = *(const s16x8*)(krow1 + hi * 8);
    s16x8 k11 = *(const s16x8*)(krow1 + 32 + hi * 8);
    s16x8 bv[4];
#pragma unroll
    for (int nt = 0; nt < 4; ++nt)
      bv[nt] = *(const s16x8*)&vT[(size_t)(b * 64 + nt * 16 + lc) * 2048 + kvb + hi * 8];

    f32x4 sc[2][2];
#pragma unroll
    for (int sub = 0; sub < 2; ++sub) {
      sc[sub][0] = (f32x4){0.f, 0.f, 0.f, 0.f};
      sc[sub][1] = (f32x4){0.f, 0.f, 0.f, 0.f};
      sc[sub][0] = MFMA_BF16(aq[sub][0], k00, sc[sub][0]);
      sc[sub][0] = MFMA_BF16(aq[sub][1], k01, sc[sub][0]);
      sc[sub][1] = MFMA_BF16(aq[sub][0], k10, sc[sub][1]);
      sc[sub][1] = MFMA_BF16(aq[sub][1], k11, sc[sub][1]);
    }

    if (kvb + 31 <= q0) {  // tile fully below diagonal: no masks
#pragma unroll
      for (int sub = 0; sub < 2; ++sub)
#pragma unroll
        for (int r = 0; r < 4; ++r) {
          float p0 = exp2f(sc[sub][0][r] * SL);
          float p1 = exp2f(sc[sub][1][r] * SL);
          lrow[sub][r] += p0 + p1;
          Pw[(sub * 16 + hi * 4 + r) * 40 + lc] = f2bf_t(p0);
          Pw[(sub * 16 + hi * 4 + r) * 40 + 16 + lc] = f2bf_t(p1);
        }
    } else {  // diagonal tile: causal masks
#pragma unroll
      for (int sub = 0; sub < 2; ++sub)
#pragma unroll
        for (int r = 0; r < 4; ++r) {
          const int qt = q0 + sub * 16 + hi * 4 + r;
          const int kv0 = kvb + lc;
          float p0 = (kv0 <= qt) ? exp2f(sc[sub][0][r] * SL) : 0.f;
          float p1 = (kv0 + 16 <= qt) ? exp2f(sc[sub][1][r] * SL) : 0.f;
          lrow[sub][r] += p0 + p1;
          Pw[(sub * 16 + hi * 4 + r) * 40 + lc] = f2bf_t(p0);
          Pw[(sub * 16 + hi * 4 + r) * 40 + 16 + lc] = f2bf_t(p1);
        }
    }
    asm volatile("s_waitcnt lgkmcnt(0)" ::: "memory");
    s16x8 pa0 = *(const s16x8*)&Pw[lc * 40 + hi * 8];
    s16x8 pa1 = *(const s16x8*)&Pw[(16 + lc) * 40 + hi * 8];
#pragma unroll
    for (int nt = 0; nt < 4; ++nt) {
      o[0][nt] = MFMA_BF16(pa0, bv[nt], o[0][nt]);
      o[1][nt] = MFMA_BF16(pa1, bv[nt], o[1][nt]);
    }
  }

#pragma unroll
  for (int sub = 0; sub < 2; ++sub)
#pragma unroll
    for (int r = 0; r < 4; ++r) {
      float l = lrow[sub][r];
      l += __shfl_xor(l, 1);
      l += __shfl_xor(l, 2);
      l += __shfl_xor(l, 4);
      l += __shfl_xor(l, 8);
      lrow[sub][r] = l;
    }

  if (lc == 0) {
#pragma unroll
    for (int sub = 0; sub < 2; ++sub)
#pragma unroll
      for (int r = 0; r < 4; ++r) Pl[w][sub * 16 + hi * 4 + r] = lrow[sub][r];
  }
  float* Pow = &PoS[w][0][0];
#pragma unroll
  for (int sub = 0; sub < 2; ++sub)
#pragma unroll
    for (int nt = 0; nt < 4; ++nt)
#pragma unroll
      for (int r = 0; r < 4; ++r)
        Pow[(sub * 16 + hi * 4 + r) * 66 + nt * 16 + lc] = o[sub][nt][r];
  __syncthreads();

#pragma unroll
  for (int rr = 0; rr < 8; ++rr) {
    const int row = w * 8 + rr;
    float L = Pl[0][row] + Pl[1][row] + Pl[2][row] + Pl[3][row];
    float val = PoS[0][row][lane] + PoS[1][row][lane] + PoS[2][row][lane] + PoS[3][row][lane];
    out[(size_t)(brow + q0 + row) * 64 + lane] = val / L;
  }
}

extern "C" void kernel_launch(void* const* d_in, const int* in_sizes, int n_in,
                              void* d_out, int out_size, void* d_ws, size_t ws_size,
                              hipStream_t stream) {
  (void)in_sizes; (void)n_in; (void)out_size; (void)ws_size;
  const float* x = (const float*)d_in[0];
  const float* Wq = (const float*)d_in[1];
  const float* Wk = (const float*)d_in[2];
  const float* Wv = (const float*)d_in[3];
  float* out = (float*)d_out;

  u16* wsu = (u16*)d_ws;
  u16* Wt = wsu;                      // 192*1024
  u16* qb = Wt + 192 * 1024;          // 8*2048*64
  u16* kb = qb + 8 * 2048 * 64;       // 8*2048*64
  u16* vT = kb + 8 * 2048 * 64;       // 8*64*2048
  // total ws use: 6,684,672 bytes

  wt_convert<<<48, 256, 0, stream>>>(Wq, Wk, Wv, Wt);
  qkv_gemm<<<1024, 256, 0, stream>>>(x, Wt, qb, kb, vT);
  attn_fwd<<<512, 256, 0, stream>>>(qb, kb, vT, out);
}

// Round 7
// 62.384 us; speedup vs baseline: 2.1284x; 1.3317x over previous
//
#include <hip/hip_runtime.h>

typedef unsigned short u16;
typedef unsigned int u32;
typedef float f32x4 __attribute__((ext_vector_type(4)));
typedef short s16x8 __attribute__((ext_vector_type(8)));

#define MFMA_BF16(a, b, c) __builtin_amdgcn_mfma_f32_16x16x32_bf16((a), (b), (c), 0, 0, 0)

// Problem constants: B=8, T=2048, D=1024, HS=64; scale = 1/sqrt(2048) (per reference!)

__device__ __forceinline__ u16 f2bf(float f) {
  union { float f; u32 u; } v; v.f = f;
  u32 u = v.u;
  return (u16)((u + 0x7FFFu + ((u >> 16) & 1u)) >> 16);  // RNE f32->bf16
}
__device__ __forceinline__ u16 f2bf_t(float f) {  // truncating f32->bf16 (P tile only)
  union { float f; u32 u; } v; v.f = f;
  return (u16)(v.u >> 16);
}
__device__ __forceinline__ s16x8 pack_bf8(float4 a, float4 b) {
  union { u32 d[4]; s16x8 v; } u;
  u.d[0] = (u32)f2bf(a.x) | ((u32)f2bf(a.y) << 16);
  u.d[1] = (u32)f2bf(a.z) | ((u32)f2bf(a.w) << 16);
  u.d[2] = (u32)f2bf(b.x) | ((u32)f2bf(b.y) << 16);
  u.d[3] = (u32)f2bf(b.z) | ((u32)f2bf(b.w) << 16);
  return u.v;
}

// ---- Kernel 1: W [1024][64] f32 x3 -> Wt2 bf16 in K-MAJOR layout:
// element (row, d) -> Wt2[((d>>3)*192 + row)*8 + (d&7)], rows: q 0-63, k 64-127, v 128-191.
// So the 12 B-fragments of one k-step sit in one contiguous 3KB window.
__global__ __launch_bounds__(256) void wt_convert(const float* __restrict__ Wq,
                                                  const float* __restrict__ Wk,
                                                  const float* __restrict__ Wv,
                                                  u16* __restrict__ Wt2) {
  __shared__ u16 Ls[64][70];
  const int bid = blockIdx.x;
  const int m = bid >> 4, d0 = (bid & 15) * 64;
  const float* W = (m == 0) ? Wq : (m == 1) ? Wk : Wv;
  const int t = threadIdx.x;
  {
    const int dr = t >> 2, hc = (t & 3) * 16;
    const float4* src = (const float4*)(W + (size_t)(d0 + dr) * 64 + hc);
    float4 f0 = src[0], f1 = src[1], f2 = src[2], f3 = src[3];
    float fl[16] = {f0.x, f0.y, f0.z, f0.w, f1.x, f1.y, f1.z, f1.w,
                    f2.x, f2.y, f2.z, f2.w, f3.x, f3.y, f3.z, f3.w};
#pragma unroll
    for (int j = 0; j < 8; ++j) {
      u32 pk = (u32)f2bf(fl[2 * j]) | ((u32)f2bf(fl[2 * j + 1]) << 16);
      *(u32*)&Ls[dr][hc + 2 * j] = pk;
    }
  }
  __syncthreads();
  {
    const int h = t >> 2, dcs = (t & 3) * 16;
    const int row = m * 64 + h;
    u32 po[8];
#pragma unroll
    for (int j = 0; j < 8; ++j)
      po[j] = (u32)Ls[dcs + 2 * j][h] | ((u32)Ls[dcs + 2 * j + 1][h] << 16);
    const int kg0 = (d0 + dcs) >> 3;
    *(uint4*)&Wt2[((size_t)kg0 * 192 + row) * 8] = make_uint4(po[0], po[1], po[2], po[3]);
    *(uint4*)&Wt2[((size_t)(kg0 + 1) * 192 + row) * 8] = make_uint4(po[4], po[5], po[6], po[7]);
  }
}

// ---- Kernel 2: QKV projection, BARRIER-FREE K-split GEMM.
// C[16384,192] = X[16384,1024] @ W[1024,192], bf16 MFMA.
// grid 1024 x 256 threads (4 waves). Wave w: full 16-row m-tile x all 12 n-tiles
// over K-quarter [w*256, w*256+256). No LDS staging, no in-loop barrier:
//  - x A-frags loaded directly (each element read exactly once chip-wide),
//  - W B-frags from k-major Wt2: 12 frags in one 3KB window (imm offsets, L1-resident).
// End: waves 1-3 publish f32 partials to LDS; ONE barrier; wave 0 merges + writes.
// 4 blocks/CU (LDS 37.6KB) = 16 waves/CU.
__global__ __launch_bounds__(256) void qkv_gemm(const float* __restrict__ x,
                                                const u16* __restrict__ Wt2,
                                                u16* __restrict__ qo,
                                                u16* __restrict__ ko,
                                                u16* __restrict__ vTo) {
  __shared__ float M[3][16][196];  // 196 pad: hi-groups land 2-way on banks (free)
  const int tid = threadIdx.x, lane = tid & 63, w = tid >> 6;
  const int lc = lane & 15, hi = lane >> 4;
  const int m0 = blockIdx.x * 16;

  f32x4 acc[12];
#pragma unroll
  for (int i = 0; i < 12; ++i) acc[i] = (f32x4){0.f, 0.f, 0.f, 0.f};

  // A: lane -> row=lc, k-offset hi*8 within the 32-wide k-step
  const float* xp = x + (size_t)(m0 + lc) * 1024 + w * 256 + hi * 8;
  // B: lane -> row(col of C)=j*16+lc, same k-offset; k-major base per (w, t, hi)
  const u16* wp = Wt2 + (size_t)(w * 32 + hi) * 1536 + lc * 8;

  for (int t = 0; t < 8; ++t) {
    float4 xa = *(const float4*)(xp + t * 32);
    float4 xb = *(const float4*)(xp + t * 32 + 4);
    s16x8 aq = pack_bf8(xa, xb);
    const u16* wk = wp + (size_t)t * 4 * 1536;
#pragma unroll
    for (int j = 0; j < 12; ++j) {
      s16x8 bf = *(const s16x8*)(wk + j * 128);  // j*256B imm offset
      acc[j] = MFMA_BF16(aq, bf, acc[j]);
    }
  }

  // publish partials (waves 1..3), merge + write (wave 0)
  if (w > 0) {
#pragma unroll
    for (int j = 0; j < 12; ++j)
#pragma unroll
      for (int r = 0; r < 4; ++r) M[w - 1][hi * 4 + r][j * 16 + lc] = acc[j][r];
  }
  __syncthreads();
  if (w == 0) {
#pragma unroll
    for (int j = 0; j < 12; ++j) {
#pragma unroll
      for (int r = 0; r < 4; ++r) {
        const int row = hi * 4 + r, n = j * 16 + lc;
        float val = acc[j][r] + M[0][row][n] + M[1][row][n] + M[2][row][n];
        u16 bvv = f2bf(val);
        const int gr = m0 + row;
        if (j < 4) {
          qo[gr * 64 + n] = bvv;
        } else if (j < 8) {
          ko[gr * 64 + (n - 64)] = bvv;
        } else {
          int b = gr >> 11, t2 = gr & 2047;
          vTo[((b << 6) + (n - 128)) * 2048 + t2] = bvv;
        }
      }
    }
  }
}

// ---- Kernel 3: causal flash attention, no-max softmax. 256 threads = 4 waves.
// (unchanged from round 5: ~18us)
__global__ __launch_bounds__(256, 2) void attn_fwd(const u16* __restrict__ qb,
                                                   const u16* __restrict__ kb,
                                                   const u16* __restrict__ vT,
                                                   float* __restrict__ out) {
  __shared__ float PoS[4][32][66];  // per-wave merge buffer; P tile [32][40]u16 unioned in
  __shared__ float Pl[4][32];       // per-wave denominator partials
  const int tid = threadIdx.x, lane = tid & 63, w = tid >> 6;
  const int lc = lane & 15, hi = lane >> 4;
  const int bid = blockIdx.x;
  const int b = bid & 7, v = 63 - (bid >> 3);  // batch, q-tile id (heavy-first)
  const int q0 = v * 32;                       // q-tile base row within batch
  const int brow = b * 2048;
  u16* Pw = (u16*)&PoS[w][0][0];  // [32][40] u16 view, per-wave

  s16x8 aq[2][2];
#pragma unroll
  for (int sub = 0; sub < 2; ++sub) {
    const u16* qrow = qb + (size_t)(brow + q0 + sub * 16 + lc) * 64;
    aq[sub][0] = *(const s16x8*)(qrow + hi * 8);
    aq[sub][1] = *(const s16x8*)(qrow + 32 + hi * 8);
  }

  f32x4 o[2][4];
  float lrow[2][4];
#pragma unroll
  for (int sub = 0; sub < 2; ++sub)
#pragma unroll
    for (int i = 0; i < 4; ++i) {
      o[sub][i] = (f32x4){0.f, 0.f, 0.f, 0.f};
      lrow[sub][i] = 0.f;
    }

  const float SL = 0.031879357f;  // (1/sqrt(2048)) * log2(e)
  const int nk = v + 1;           // causal kv-tiles of 32 for this q-tile
  const int c = (nk + 3) >> 2;    // chunk per split-wave (4-way)
  const int s = w;
  const int it0 = s * c;
  const int it1 = min(it0 + c, nk);

  const u16* kbase = kb + (size_t)brow * 64;

  for (int it = it0; it < it1; ++it) {
    const int kvb = it * 32;
    const u16* krow0 = kbase + (size_t)(kvb + lc) * 64;
    const u16* krow1 = kbase + (size_t)(kvb + 16 + lc) * 64;
    s16x8 k00 = *(const s16x8*)(krow0 + hi * 8);
    s16x8 k01 = *(const s16x8*)(krow0 + 32 + hi * 8);
    s16x8 k10 = *(const s16x8*)(krow1 + hi * 8);
    s16x8 k11 = *(const s16x8*)(krow1 + 32 + hi * 8);
    s16x8 bv[4];
#pragma unroll
    for (int nt = 0; nt < 4; ++nt)
      bv[nt] = *(const s16x8*)&vT[(size_t)(b * 64 + nt * 16 + lc) * 2048 + kvb + hi * 8];

    f32x4 sc[2][2];
#pragma unroll
    for (int sub = 0; sub < 2; ++sub) {
      sc[sub][0] = (f32x4){0.f, 0.f, 0.f, 0.f};
      sc[sub][1] = (f32x4){0.f, 0.f, 0.f, 0.f};
      sc[sub][0] = MFMA_BF16(aq[sub][0], k00, sc[sub][0]);
      sc[sub][0] = MFMA_BF16(aq[sub][1], k01, sc[sub][0]);
      sc[sub][1] = MFMA_BF16(aq[sub][0], k10, sc[sub][1]);
      sc[sub][1] = MFMA_BF16(aq[sub][1], k11, sc[sub][1]);
    }

    if (kvb + 31 <= q0) {  // tile fully below diagonal: no masks
#pragma unroll
      for (int sub = 0; sub < 2; ++sub)
#pragma unroll
        for (int r = 0; r < 4; ++r) {
          float p0 = exp2f(sc[sub][0][r] * SL);
          float p1 = exp2f(sc[sub][1][r] * SL);
          lrow[sub][r] += p0 + p1;
          Pw[(sub * 16 + hi * 4 + r) * 40 + lc] = f2bf_t(p0);
          Pw[(sub * 16 + hi * 4 + r) * 40 + 16 + lc] = f2bf_t(p1);
        }
    } else {  // diagonal tile: causal masks
#pragma unroll
      for (int sub = 0; sub < 2; ++sub)
#pragma unroll
        for (int r = 0; r < 4; ++r) {
          const int qt = q0 + sub * 16 + hi * 4 + r;
          const int kv0 = kvb + lc;
          float p0 = (kv0 <= qt) ? exp2f(sc[sub][0][r] * SL) : 0.f;
          float p1 = (kv0 + 16 <= qt) ? exp2f(sc[sub][1][r] * SL) : 0.f;
          lrow[sub][r] += p0 + p1;
          Pw[(sub * 16 + hi * 4 + r) * 40 + lc] = f2bf_t(p0);
          Pw[(sub * 16 + hi * 4 + r) * 40 + 16 + lc] = f2bf_t(p1);
        }
    }
    asm volatile("s_waitcnt lgkmcnt(0)" ::: "memory");
    s16x8 pa0 = *(const s16x8*)&Pw[lc * 40 + hi * 8];
    s16x8 pa1 = *(const s16x8*)&Pw[(16 + lc) * 40 + hi * 8];
#pragma unroll
    for (int nt = 0; nt < 4; ++nt) {
      o[0][nt] = MFMA_BF16(pa0, bv[nt], o[0][nt]);
      o[1][nt] = MFMA_BF16(pa1, bv[nt], o[1][nt]);
    }
  }

#pragma unroll
  for (int sub = 0; sub < 2; ++sub)
#pragma unroll
    for (int r = 0; r < 4; ++r) {
      float l = lrow[sub][r];
      l += __shfl_xor(l, 1);
      l += __shfl_xor(l, 2);
      l += __shfl_xor(l, 4);
      l += __shfl_xor(l, 8);
      lrow[sub][r] = l;
    }

  if (lc == 0) {
#pragma unroll
    for (int sub = 0; sub < 2; ++sub)
#pragma unroll
      for (int r = 0; r < 4; ++r) Pl[w][sub * 16 + hi * 4 + r] = lrow[sub][r];
  }
  float* Pow = &PoS[w][0][0];
#pragma unroll
  for (int sub = 0; sub < 2; ++sub)
#pragma unroll
    for (int nt = 0; nt < 4; ++nt)
#pragma unroll
      for (int r = 0; r < 4; ++r)
        Pow[(sub * 16 + hi * 4 + r) * 66 + nt * 16 + lc] = o[sub][nt][r];
  __syncthreads();

#pragma unroll
  for (int rr = 0; rr < 8; ++rr) {
    const int row = w * 8 + rr;
    float L = Pl[0][row] + Pl[1][row] + Pl[2][row] + Pl[3][row];
    float val = PoS[0][row][lane] + PoS[1][row][lane] + PoS[2][row][lane] + PoS[3][row][lane];
    out[(size_t)(brow + q0 + row) * 64 + lane] = val / L;
  }
}

extern "C" void kernel_launch(void* const* d_in, const int* in_sizes, int n_in,
                              void* d_out, int out_size, void* d_ws, size_t ws_size,
                              hipStream_t stream) {
  (void)in_sizes; (void)n_in; (void)out_size; (void)ws_size;
  const float* x = (const float*)d_in[0];
  const float* Wq = (const float*)d_in[1];
  const float* Wk = (const float*)d_in[2];
  const float* Wv = (const float*)d_in[3];
  float* out = (float*)d_out;

  u16* wsu = (u16*)d_ws;
  u16* Wt = wsu;                      // 192*1024 (k-major layout)
  u16* qb = Wt + 192 * 1024;          // 8*2048*64
  u16* kb = qb + 8 * 2048 * 64;       // 8*2048*64
  u16* vT = kb + 8 * 2048 * 64;       // 8*64*2048
  // total ws use: 6,684,672 bytes

  wt_convert<<<48, 256, 0, stream>>>(Wq, Wk, Wv, Wt);
  qkv_gemm<<<1024, 256, 0, stream>>>(x, Wt, qb, kb, vT);
  attn_fwd<<<512, 256, 0, stream>>>(qb, kb, vT, out);
}

// Round 8
// 56.979 us; speedup vs baseline: 2.3302x; 1.0949x over previous
//
#include <hip/hip_runtime.h>

typedef unsigned short u16;
typedef unsigned int u32;
typedef float f32x4 __attribute__((ext_vector_type(4)));
typedef short s16x8 __attribute__((ext_vector_type(8)));

#define MFMA_BF16(a, b, c) __builtin_amdgcn_mfma_f32_16x16x32_bf16((a), (b), (c), 0, 0, 0)

// Problem constants: B=8, T=2048, D=1024, HS=64; scale = 1/sqrt(2048) (per reference!)

__device__ __forceinline__ u16 f2bf(float f) {
  union { float f; u32 u; } v; v.f = f;
  u32 u = v.u;
  return (u16)((u + 0x7FFFu + ((u >> 16) & 1u)) >> 16);  // RNE f32->bf16
}
__device__ __forceinline__ u16 f2bf_t(float f) {  // truncating f32->bf16 (P tile only)
  union { float f; u32 u; } v; v.f = f;
  return (u16)(v.u >> 16);
}
__device__ __forceinline__ s16x8 pack_bf8(float4 a, float4 b) {
  union { u32 d[4]; s16x8 v; } u;
  u.d[0] = (u32)f2bf(a.x) | ((u32)f2bf(a.y) << 16);
  u.d[1] = (u32)f2bf(a.z) | ((u32)f2bf(a.w) << 16);
  u.d[2] = (u32)f2bf(b.x) | ((u32)f2bf(b.y) << 16);
  u.d[3] = (u32)f2bf(b.z) | ((u32)f2bf(b.w) << 16);
  return u.v;
}
__device__ __forceinline__ void gload_lds16(const u16* g, u16* l) {
  __builtin_amdgcn_global_load_lds((const __attribute__((address_space(1))) u32*)(const void*)g,
                                   (__attribute__((address_space(3))) u32*)(void*)l, 16, 0, 0);
}

// ---- Kernel 1: W [1024][64] f32 x3 -> Wt3 bf16 [16 kstep][192 row][64 k]
// (rows: q 0-63, k 64-127, v 128-191). Each k-step's W is one contiguous 24KB chunk.
__global__ __launch_bounds__(256) void wt_convert(const float* __restrict__ Wq,
                                                  const float* __restrict__ Wk,
                                                  const float* __restrict__ Wv,
                                                  u16* __restrict__ Wt3) {
  __shared__ u16 Ls[64][70];
  const int bid = blockIdx.x;
  const int m = bid >> 4, kstep = bid & 15, d0 = kstep * 64;
  const float* W = (m == 0) ? Wq : (m == 1) ? Wk : Wv;
  const int t = threadIdx.x;
  {
    const int dr = t >> 2, hc = (t & 3) * 16;
    const float4* src = (const float4*)(W + (size_t)(d0 + dr) * 64 + hc);
    float4 f0 = src[0], f1 = src[1], f2 = src[2], f3 = src[3];
    float fl[16] = {f0.x, f0.y, f0.z, f0.w, f1.x, f1.y, f1.z, f1.w,
                    f2.x, f2.y, f2.z, f2.w, f3.x, f3.y, f3.z, f3.w};
#pragma unroll
    for (int j = 0; j < 8; ++j) {
      u32 pk = (u32)f2bf(fl[2 * j]) | ((u32)f2bf(fl[2 * j + 1]) << 16);
      *(u32*)&Ls[dr][hc + 2 * j] = pk;
    }
  }
  __syncthreads();
  {
    const int h = t >> 2, dcs = (t & 3) * 16;
    const int grow = m * 64 + h;
    u32 po[8];
#pragma unroll
    for (int j = 0; j < 8; ++j)
      po[j] = (u32)Ls[dcs + 2 * j][h] | ((u32)Ls[dcs + 2 * j + 1][h] << 16);
    u16* dst = Wt3 + (size_t)kstep * 12288 + grow * 64 + dcs;
    *(uint4*)&dst[0] = make_uint4(po[0], po[1], po[2], po[3]);
    *(uint4*)&dst[8] = make_uint4(po[4], po[5], po[6], po[7]);
  }
}

// ---- Kernel 2: QKV projection. C[16384,192] = X[16384,1024] @ W[1024,192], bf16 MFMA.
// 2-phase pipelined tile loop (guide T3-min): BM=32, BN=192, BK=64, 512 thr (8 waves),
// grid 512 (2 blocks/CU, 16 waves/CU). Wave (ntg=w&3, ksub=w>>2): 32 rows x 3 n-tiles
// x one 32-wide k-half -> 5 LDS b128 reads per 6 MFMA. k-split merged via LDS at end.
// W staged by global_load_lds (24KB/step); x reg-staged with f32->bf16 convert.
// LDS tiles are [row][64]bf16 (128B rows) with granule-XOR swizzle g^=(row&7) applied
// on BOTH sides (pre-swizzled staging source / swizzled read) -> 2-way banks (free).
__global__ __launch_bounds__(512) void qkv_gemm(const float* __restrict__ x,
                                                const u16* __restrict__ Wt3,
                                                u16* __restrict__ qo,
                                                u16* __restrict__ ko,
                                                u16* __restrict__ vTo) {
  __shared__ u16 Wl[2][12288];  // 2 x 24KB: [192 row][64 k] bf16, swizzled
  __shared__ u16 Xs[2][2048];   // 2 x 4KB:  [32 row][64 k] bf16, swizzled
  const int tid = threadIdx.x, lane = tid & 63, w = tid >> 6;
  const int lc = lane & 15, hi = lane >> 4;
  const int m0 = blockIdx.x * 32;
  const int ntg = w & 3, ksub = w >> 2;  // n-tile group [ntg*3,+3), k-half

  f32x4 acc[2][3];  // [msub][j]
#pragma unroll
  for (int a = 0; a < 2; ++a)
#pragma unroll
    for (int i = 0; i < 3; ++i) acc[a][i] = (f32x4){0.f, 0.f, 0.f, 0.f};

  // W staging: wave w issues instrs i = w*3..w*3+2; lane l covers row r = i*8+(l>>3),
  // source granule gs = (l&7)^((l>>3)&7)  (inverse of read swizzle; i*8 = 0 mod 8)
  const int wr_r = (lane >> 3);                       // row-in-instr 0..7
  const int wr_g = (lane & 7) ^ ((lane >> 3) & 7);    // source granule
  // x staging (threads 0..255): row = tid>>3, src granule32 sg = tid&7
  const int xrow = tid >> 3, xsg = tid & 7;
  const int xg = xsg ^ (xrow & 7);                    // swizzled dest granule16
  const float* xptr = x + (size_t)(m0 + xrow) * 1024 + xsg * 8;

  // read offsets (u16 elements), granule-swizzled
  const int ga = ((ksub * 4 + hi) ^ (lc & 7)) * 8;    // A/B k-granule offset

  auto stage_w = [&](int t, int buf) {
#pragma unroll
    for (int c = 0; c < 3; ++c) {
      const int i = w * 3 + c;
      const int r = i * 8 + wr_r;
      gload_lds16(Wt3 + (size_t)t * 12288 + r * 64 + wr_g * 8, &Wl[buf][i * 512]);
    }
  };

  // prologue: stage step 0
  {
    stage_w(0, 0);
    if (tid < 256) {
      float4 xa = *(const float4*)xptr;
      float4 xb = *(const float4*)(xptr + 4);
      s16x8 p = pack_bf8(xa, xb);
      *(s16x8*)&Xs[0][xrow * 64 + xg * 8] = p;
    }
  }
  __syncthreads();
  int buf = 0;

  for (int t = 0; t < 16; ++t) {
    float4 xa, xb;
    if (t < 15) {
      xa = *(const float4*)(xptr + (t + 1) * 64);
      xb = *(const float4*)(xptr + (t + 1) * 64 + 4);
      stage_w(t + 1, buf ^ 1);
    }
    // compute current step from buf
    s16x8 a0 = *(const s16x8*)&Xs[buf][(0 * 16 + lc) * 64 + ga];
    s16x8 a1 = *(const s16x8*)&Xs[buf][(1 * 16 + lc) * 64 + ga];
#pragma unroll
    for (int j = 0; j < 3; ++j) {
      const int row = (ntg * 3 + j) * 16 + lc;
      s16x8 bfr = *(const s16x8*)&Wl[buf][row * 64 + ga];
      acc[0][j] = MFMA_BF16(a0, bfr, acc[0][j]);
      acc[1][j] = MFMA_BF16(a1, bfr, acc[1][j]);
    }
    if (t < 15) {
      if (tid < 256) {
        s16x8 p = pack_bf8(xa, xb);
        *(s16x8*)&Xs[buf ^ 1][xrow * 64 + xg * 8] = p;
      }
      __syncthreads();
      buf ^= 1;
    }
  }

  // k-split merge: ksub=1 waves publish, ksub=0 waves add + write out.
  float* M = (float*)&Wl[0][0];  // 4 ntg x 32 row x 48 col f32 = 24KB (Wl[0] reuse)
  __syncthreads();
  if (ksub == 1) {
#pragma unroll
    for (int ms = 0; ms < 2; ++ms)
#pragma unroll
      for (int j = 0; j < 3; ++j)
#pragma unroll
        for (int r = 0; r < 4; ++r)
          M[ntg * 1536 + (ms * 16 + hi * 4 + r) * 48 + j * 16 + lc] = acc[ms][j][r];
  }
  __syncthreads();
  if (ksub == 0) {
#pragma unroll
    for (int ms = 0; ms < 2; ++ms)
#pragma unroll
      for (int j = 0; j < 3; ++j) {
        const int nt = ntg * 3 + j;
#pragma unroll
        for (int r = 0; r < 4; ++r) {
          const int row = ms * 16 + hi * 4 + r;
          float val = acc[ms][j][r] + M[ntg * 1536 + row * 48 + j * 16 + lc];
          u16 bvv = f2bf(val);
          const int gr = m0 + row;
          const int n = nt * 16 + lc;
          if (nt < 4) {
            qo[gr * 64 + n] = bvv;
          } else if (nt < 8) {
            ko[gr * 64 + (n - 64)] = bvv;
          } else {
            int b = gr >> 11, t2 = gr & 2047;
            vTo[((b << 6) + (n - 128)) * 2048 + t2] = bvv;
          }
        }
      }
  }
}

// ---- Kernel 3: causal flash attention, no-max softmax. 256 threads = 4 waves.
// (unchanged from round 5/7: ~10us)
__global__ __launch_bounds__(256, 2) void attn_fwd(const u16* __restrict__ qb,
                                                   const u16* __restrict__ kb,
                                                   const u16* __restrict__ vT,
                                                   float* __restrict__ out) {
  __shared__ float PoS[4][32][66];  // per-wave merge buffer; P tile [32][40]u16 unioned in
  __shared__ float Pl[4][32];       // per-wave denominator partials
  const int tid = threadIdx.x, lane = tid & 63, w = tid >> 6;
  const int lc = lane & 15, hi = lane >> 4;
  const int bid = blockIdx.x;
  const int b = bid & 7, v = 63 - (bid >> 3);  // batch, q-tile id (heavy-first)
  const int q0 = v * 32;                       // q-tile base row within batch
  const int brow = b * 2048;
  u16* Pw = (u16*)&PoS[w][0][0];  // [32][40] u16 view, per-wave

  s16x8 aq[2][2];
#pragma unroll
  for (int sub = 0; sub < 2; ++sub) {
    const u16* qrow = qb + (size_t)(brow + q0 + sub * 16 + lc) * 64;
    aq[sub][0] = *(const s16x8*)(qrow + hi * 8);
    aq[sub][1] = *(const s16x8*)(qrow + 32 + hi * 8);
  }

  f32x4 o[2][4];
  float lrow[2][4];
#pragma unroll
  for (int sub = 0; sub < 2; ++sub)
#pragma unroll
    for (int i = 0; i < 4; ++i) {
      o[sub][i] = (f32x4){0.f, 0.f, 0.f, 0.f};
      lrow[sub][i] = 0.f;
    }

  const float SL = 0.031879357f;  // (1/sqrt(2048)) * log2(e)
  const int nk = v + 1;           // causal kv-tiles of 32 for this q-tile
  const int c = (nk + 3) >> 2;    // chunk per split-wave (4-way)
  const int s = w;
  const int it0 = s * c;
  const int it1 = min(it0 + c, nk);

  const u16* kbase = kb + (size_t)brow * 64;

  for (int it = it0; it < it1; ++it) {
    const int kvb = it * 32;
    const u16* krow0 = kbase + (size_t)(kvb + lc) * 64;
    const u16* krow1 = kbase + (size_t)(kvb + 16 + lc) * 64;
    s16x8 k00 = *(const s16x8*)(krow0 + hi * 8);
    s16x8 k01 = *(const s16x8*)(krow0 + 32 + hi * 8);
    s16x8 k10 = *(const s16x8*)(krow1 + hi * 8);
    s16x8 k11 = *(const s16x8*)(krow1 + 32 + hi * 8);
    s16x8 bv[4];
#pragma unroll
    for (int nt = 0; nt < 4; ++nt)
      bv[nt] = *(const s16x8*)&vT[(size_t)(b * 64 + nt * 16 + lc) * 2048 + kvb + hi * 8];

    f32x4 sc[2][2];
#pragma unroll
    for (int sub = 0; sub < 2; ++sub) {
      sc[sub][0] = (f32x4){0.f, 0.f, 0.f, 0.f};
      sc[sub][1] = (f32x4){0.f, 0.f, 0.f, 0.f};
      sc[sub][0] = MFMA_BF16(aq[sub][0], k00, sc[sub][0]);
      sc[sub][0] = MFMA_BF16(aq[sub][1], k01, sc[sub][0]);
      sc[sub][1] = MFMA_BF16(aq[sub][0], k10, sc[sub][1]);
      sc[sub][1] = MFMA_BF16(aq[sub][1], k11, sc[sub][1]);
    }

    if (kvb + 31 <= q0) {  // tile fully below diagonal: no masks
#pragma unroll
      for (int sub = 0; sub < 2; ++sub)
#pragma unroll
        for (int r = 0; r < 4; ++r) {
          float p0 = exp2f(sc[sub][0][r] * SL);
          float p1 = exp2f(sc[sub][1][r] * SL);
          lrow[sub][r] += p0 + p1;
          Pw[(sub * 16 + hi * 4 + r) * 40 + lc] = f2bf_t(p0);
          Pw[(sub * 16 + hi * 4 + r) * 40 + 16 + lc] = f2bf_t(p1);
        }
    } else {  // diagonal tile: causal masks
#pragma unroll
      for (int sub = 0; sub < 2; ++sub)
#pragma unroll
        for (int r = 0; r < 4; ++r) {
          const int qt = q0 + sub * 16 + hi * 4 + r;
          const int kv0 = kvb + lc;
          float p0 = (kv0 <= qt) ? exp2f(sc[sub][0][r] * SL) : 0.f;
          float p1 = (kv0 + 16 <= qt) ? exp2f(sc[sub][1][r] * SL) : 0.f;
          lrow[sub][r] += p0 + p1;
          Pw[(sub * 16 + hi * 4 + r) * 40 + lc] = f2bf_t(p0);
          Pw[(sub * 16 + hi * 4 + r) * 40 + 16 + lc] = f2bf_t(p1);
        }
    }
    asm volatile("s_waitcnt lgkmcnt(0)" ::: "memory");
    s16x8 pa0 = *(const s16x8*)&Pw[lc * 40 + hi * 8];
    s16x8 pa1 = *(const s16x8*)&Pw[(16 + lc) * 40 + hi * 8];
#pragma unroll
    for (int nt = 0; nt < 4; ++nt) {
      o[0][nt] = MFMA_BF16(pa0, bv[nt], o[0][nt]);
      o[1][nt] = MFMA_BF16(pa1, bv[nt], o[1][nt]);
    }
  }

#pragma unroll
  for (int sub = 0; sub < 2; ++sub)
#pragma unroll
    for (int r = 0; r < 4; ++r) {
      float l = lrow[sub][r];
      l += __shfl_xor(l, 1);
      l += __shfl_xor(l, 2);
      l += __shfl_xor(l, 4);
      l += __shfl_xor(l, 8);
      lrow[sub][r] = l;
    }

  if (lc == 0) {
#pragma unroll
    for (int sub = 0; sub < 2; ++sub)
#pragma unroll
      for (int r = 0; r < 4; ++r) Pl[w][sub * 16 + hi * 4 + r] = lrow[sub][r];
  }
  float* Pow = &PoS[w][0][0];
#pragma unroll
  for (int sub = 0; sub < 2; ++sub)
#pragma unroll
    for (int nt = 0; nt < 4; ++nt)
#pragma unroll
      for (int r = 0; r < 4; ++r)
        Pow[(sub * 16 + hi * 4 + r) * 66 + nt * 16 + lc] = o[sub][nt][r];
  __syncthreads();

#pragma unroll
  for (int rr = 0; rr < 8; ++rr) {
    const int row = w * 8 + rr;
    float L = Pl[0][row] + Pl[1][row] + Pl[2][row] + Pl[3][row];
    float val = PoS[0][row][lane] + PoS[1][row][lane] + PoS[2][row][lane] + PoS[3][row][lane];
    out[(size_t)(brow + q0 + row) * 64 + lane] = val / L;
  }
}

extern "C" void kernel_launch(void* const* d_in, const int* in_sizes, int n_in,
                              void* d_out, int out_size, void* d_ws, size_t ws_size,
                              hipStream_t stream) {
  (void)in_sizes; (void)n_in; (void)out_size; (void)ws_size;
  const float* x = (const float*)d_in[0];
  const float* Wq = (const float*)d_in[1];
  const float* Wk = (const float*)d_in[2];
  const float* Wv = (const float*)d_in[3];
  float* out = (float*)d_out;

  u16* wsu = (u16*)d_ws;
  u16* Wt = wsu;                      // 16*192*64 = 196608 (k-step-major layout)
  u16* qb = Wt + 192 * 1024;          // 8*2048*64
  u16* kb = qb + 8 * 2048 * 64;       // 8*2048*64
  u16* vT = kb + 8 * 2048 * 64;       // 8*64*2048
  // total ws use: 6,684,672 bytes

  wt_convert<<<48, 256, 0, stream>>>(Wq, Wk, Wv, Wt);
  qkv_gemm<<<512, 512, 0, stream>>>(x, Wt, qb, kb, vT);
  attn_fwd<<<512, 256, 0, stream>>>(qb, kb, vT, out);
}